// Round 11
// baseline (168.293 us; speedup 1.0000x reference)
//
#include <hip/hip_runtime.h>
#include <hip/hip_fp16.h>
#include <math.h>

#define NNODES 50000
#define NEDGES 800000
#define F      64
#define NB     782               // ceil(NNODES/64) buckets of 64 nodes
#define CAP    1408              // fixed slots per bucket
#define LIN_BLOCKS 1563          // 32 nodes / block
#define SBLK   256               // staging blocks (1 per CU)
#define SIT    13                // edges/thread in staging (256*256*13 >= NEDGES)
#define SEPB   (256 * SIT)       // 3328 edges per staging block
#define XSP    68                // padded LDS row stride (floats)

typedef unsigned short u16;
typedef unsigned int   u32;

// pack two f32 -> two bf16 (RNE)
__device__ __forceinline__ u32 f2bf2(float a, float b) {
    u32 ua = __float_as_uint(a), ub = __float_as_uint(b);
    ua = (ua + 0x7FFFu + ((ua >> 16) & 1u)) >> 16;
    ub = (ub + 0x7FFFu + ((ub >> 16) & 1u)) >> 16;
    return ua | (ub << 16);
}

#define ACC8(ev, hv) \
    a0 = fmaf(ev, __uint_as_float(hv.x << 16),         a0); \
    a1 = fmaf(ev, __uint_as_float(hv.x & 0xFFFF0000u), a1); \
    a2 = fmaf(ev, __uint_as_float(hv.y << 16),         a2); \
    a3 = fmaf(ev, __uint_as_float(hv.y & 0xFFFF0000u), a3); \
    a4 = fmaf(ev, __uint_as_float(hv.z << 16),         a4); \
    a5 = fmaf(ev, __uint_as_float(hv.z & 0xFFFF0000u), a5); \
    a6 = fmaf(ev, __uint_as_float(hv.w << 16),         a6); \
    a7 = fmaf(ev, __uint_as_float(hv.w & 0xFFFF0000u), a7)

// shared-memory layout for the linear body (aliased by the stage path)
struct LinSmem {
    float Ws[F * F];          // 16 KB
    float xs[32 * XSP];       // 8.7 KB
    float asv[F], adv[F];
};

// ---------------------------------------------------------------------------
// Linear body: h16 = bf16(x @ W) ; as_ = (xW).a_src ; ad_ = (xW).a_dst
// 32 nodes / block; 8 lanes per node, 8 output cols per lane.
// ---------------------------------------------------------------------------
__device__ __forceinline__ void linear_body(
    LinSmem& sm,
    const float* __restrict__ x, const float* __restrict__ W,
    const float* __restrict__ a_src, const float* __restrict__ a_dst,
    u16* __restrict__ h16, float* __restrict__ as_, float* __restrict__ ad_,
    int blk)
{
    const int tid = threadIdx.x;
    const int n   = tid >> 3;          // node within block 0..31
    const int c0  = (tid & 7) * 8;     // output col base
    const int node = blk * 32 + n;
    const bool valid = node < NNODES;

    for (int i = tid * 4; i < F * F; i += 1024)
        *(float4*)&sm.Ws[i] = *(const float4*)&W[i];
    if (tid < F) { sm.asv[tid] = a_src[tid]; sm.adv[tid] = a_dst[tid]; }
    if (valid) {
        const float4 v0 = *(const float4*)&x[(size_t)node * F + c0];
        const float4 v1 = *(const float4*)&x[(size_t)node * F + c0 + 4];
        *(float4*)&sm.xs[n * XSP + c0]     = v0;
        *(float4*)&sm.xs[n * XSP + c0 + 4] = v1;
    }
    __syncthreads();

    float o0=0.f,o1=0.f,o2=0.f,o3=0.f,o4=0.f,o5=0.f,o6=0.f,o7=0.f;
#pragma unroll 8
    for (int k = 0; k < F; ++k) {
        const float xv = sm.xs[n * XSP + k];
        const float4 wa = *(const float4*)&sm.Ws[k * F + c0];
        const float4 wb = *(const float4*)&sm.Ws[k * F + c0 + 4];
        o0 = fmaf(xv, wa.x, o0); o1 = fmaf(xv, wa.y, o1);
        o2 = fmaf(xv, wa.z, o2); o3 = fmaf(xv, wa.w, o3);
        o4 = fmaf(xv, wb.x, o4); o5 = fmaf(xv, wb.y, o5);
        o6 = fmaf(xv, wb.z, o6); o7 = fmaf(xv, wb.w, o7);
    }

    float vs = o0*sm.asv[c0]   + o1*sm.asv[c0+1] + o2*sm.asv[c0+2] + o3*sm.asv[c0+3]
             + o4*sm.asv[c0+4] + o5*sm.asv[c0+5] + o6*sm.asv[c0+6] + o7*sm.asv[c0+7];
    float vd = o0*sm.adv[c0]   + o1*sm.adv[c0+1] + o2*sm.adv[c0+2] + o3*sm.adv[c0+3]
             + o4*sm.adv[c0+4] + o5*sm.adv[c0+5] + o6*sm.adv[c0+6] + o7*sm.adv[c0+7];
    vs += __shfl_xor(vs, 1, 64); vs += __shfl_xor(vs, 2, 64); vs += __shfl_xor(vs, 4, 64);
    vd += __shfl_xor(vd, 1, 64); vd += __shfl_xor(vd, 2, 64); vd += __shfl_xor(vd, 4, 64);

    if (valid) {
        if ((tid & 7) == 0) { as_[node] = vs; ad_[node] = vd; }
        uint4 p;
        p.x = f2bf2(o0, o1); p.y = f2bf2(o2, o3);
        p.z = f2bf2(o4, o5); p.w = f2bf2(o6, o7);
        *(uint4*)&h16[(size_t)node * F + c0] = p;
    }
}

// ---------------------------------------------------------------------------
// K1: blocks [0,SBLK): stage REAL edges (no self loops) into fixed-CAP bucket
//     regions. Single pass over edge_index; ONE LDS atomic per edge (its
//     return value is the local slot; scatter is atomic-free).
//     blocks [SBLK..): layer-1 linear (stage latency hides under it).
// ---------------------------------------------------------------------------
__global__ __launch_bounds__(256) void stage_linear1(
    const float* __restrict__ x, const float* __restrict__ W,
    const float* __restrict__ a_src, const float* __restrict__ a_dst,
    u16* __restrict__ h16, float* __restrict__ as_, float* __restrict__ ad_,
    const int* __restrict__ src, const int* __restrict__ dst,
    int* __restrict__ gcur, u32* __restrict__ stg)
{
    __shared__ LinSmem sm;
    if (blockIdx.x < SBLK) {
        int* cnt   = (int*)&sm;          // NB ints
        int* lbase = cnt + NB;           // NB ints (aliases sm)
        for (int i = threadIdx.x; i < NB; i += 256) cnt[i] = 0;
        __syncthreads();
        const int base = blockIdx.x * SEPB;
        u32 pk_[SIT];                    // (d&63)<<16 | s
        int bp_[SIT];                    // bucket | pos<<10   (-1 = invalid)
#pragma unroll
        for (int it = 0; it < SIT; ++it) {
            const int e = base + it * 256 + threadIdx.x;
            if (e < NEDGES) {
                const int s = src[e], d = dst[e];
                pk_[it] = ((u32)(d & 63) << 16) | (u32)s;
                const int b6 = d >> 6;
                const int pos = atomicAdd(&cnt[b6], 1);
                bp_[it] = b6 | (pos << 10);
            } else {
                bp_[it] = -1; pk_[it] = 0;
            }
        }
        __syncthreads();
        for (int i = threadIdx.x; i < NB; i += 256) {
            const int c = cnt[i];
            lbase[i] = c ? (i * CAP + atomicAdd(&gcur[i], c)) : 0;
        }
        __syncthreads();
#pragma unroll
        for (int it = 0; it < SIT; ++it) {
            if (bp_[it] >= 0) {
                const int b6  = bp_[it] & 1023;
                const int pos = bp_[it] >> 10;
                stg[lbase[b6] + pos] = pk_[it];
            }
        }
        return;
    }
    linear_body(sm, x, W, a_src, a_dst, h16, as_, ad_, blockIdx.x - SBLK);
}

// ---------------------------------------------------------------------------
// K2/K3: per-bucket fused {LDS CSR build + per-edge attention} + softmax
// aggregate + bias + LeakyReLU(0.01). Self-loop handled inline (never staged).
// Block = 64 nodes (one bucket), 512 threads, 8 lanes per node.
// MODE 0 epilogue: fused layer-2 linear -> bf16 h2 + attention dots.
// MODE 1 epilogue: + residual, f32 out.
// ---------------------------------------------------------------------------
template<int MODE>
__global__ __launch_bounds__(512) void gat_agg(
    const int* __restrict__ gcur, const u32* __restrict__ stg,
    const u16* __restrict__ hin,
    const float* __restrict__ as_, const float* __restrict__ ad_,
    const float* __restrict__ bias,
    const float* __restrict__ Wn, const float* __restrict__ an_s,
    const float* __restrict__ an_d,
    u16* __restrict__ hout, float* __restrict__ as_out, float* __restrict__ ad_out,
    const float* __restrict__ resid, float* __restrict__ out)
{
    __shared__ u32  csrE[CAP];
    __shared__ int  cnt[64];     // hist, then scatter cursor
    __shared__ int  rp[64];      // local exclusive rowptr
    __shared__ float advn[64];   // ad_ for bucket nodes
    __shared__ float asnn[64];   // as_ for bucket nodes (self-loop term)
    __shared__ float Ws[MODE == 0 ? F * F : 1];
    __shared__ float asv[MODE == 0 ? F : 1], adv[MODE == 0 ? F : 1];
    __shared__ float xs[MODE == 0 ? 64 * XSP : 1];

    const int tid   = threadIdx.x;
    const int b     = blockIdx.x;
    const int nbase = b << 6;
    const int nr    = (NNODES - nbase < 64) ? (NNODES - nbase) : 64;
    const int m     = gcur[b];

    if (tid < 64) {
        cnt[tid]  = 0;
        const bool v = tid < nr;
        advn[tid] = v ? ad_[nbase + tid] : 0.f;
        asnn[tid] = v ? as_[nbase + tid] : 0.f;
    }
    if constexpr (MODE == 0) {
        for (int i = tid * 4; i < F * F; i += 2048)
            *(float4*)&Ws[i] = *(const float4*)&Wn[i];
        if (tid < F) { asv[tid] = an_s[tid]; adv[tid] = an_d[tid]; }
    }
    __syncthreads();

    // ---- build: hist
    for (int i = tid; i < m; i += 512)
        atomicAdd(&cnt[stg[b * CAP + i] >> 16], 1);
    __syncthreads();
    // ---- scan (wave 0)
    if (tid < 64) {
        const int v = cnt[tid];
        int incl = v;
#pragma unroll
        for (int off = 1; off < 64; off <<= 1) {
            const int t = __shfl_up(incl, off, 64);
            if (tid >= off) incl += t;
        }
        rp[tid]  = incl - v;
        cnt[tid] = incl - v;
    }
    __syncthreads();
    // ---- scatter + per-edge attention weight (once per edge)
    for (int i = tid; i < m; i += 512) {
        const u32 pk = stg[b * CAP + i];
        const int d6 = pk >> 16;
        const int s  = pk & 0xFFFFu;
        float r = as_[s] + advn[d6];
        r = (r > 0.f) ? r : 0.2f * r;
        const float ev = __expf(r);
        const int pos = atomicAdd(&cnt[d6], 1);
        csrE[pos] = ((u32)__half_as_ushort(__float2half(ev)) << 16) | (u32)s;
    }
    __syncthreads();

    // ---- aggregate: 8 lanes per node
    const int n   = tid >> 3;          // node 0..63
    const int l   = tid & 7;           // 16B chunk of the 128B bf16 row
    const int beg = rp[n];
    const int deg = cnt[n] - rp[n];

    float a0=0.f,a1=0.f,a2=0.f,a3=0.f,a4=0.f,a5=0.f,a6=0.f,a7=0.f;
    float z = 0.f;
    const int nfull = deg & ~3;
    int i = 0;
    for (; i < nfull; i += 4) {
        const u32 p1 = csrE[beg + i];
        const u32 p2 = csrE[beg + i + 1];
        const u32 p3 = csrE[beg + i + 2];
        const u32 p4 = csrE[beg + i + 3];
        const uint4 h1 = ((const uint4*)(hin + (size_t)(p1 & 0xFFFFu) * F))[l];
        const uint4 h2 = ((const uint4*)(hin + (size_t)(p2 & 0xFFFFu) * F))[l];
        const uint4 h3 = ((const uint4*)(hin + (size_t)(p3 & 0xFFFFu) * F))[l];
        const uint4 h4 = ((const uint4*)(hin + (size_t)(p4 & 0xFFFFu) * F))[l];
        const float e1 = __half2float(__ushort_as_half((u16)(p1 >> 16)));
        const float e2 = __half2float(__ushort_as_half((u16)(p2 >> 16)));
        const float e3 = __half2float(__ushort_as_half((u16)(p3 >> 16)));
        const float e4 = __half2float(__ushort_as_half((u16)(p4 >> 16)));
        z += (e1 + e2) + (e3 + e4);
        ACC8(e1, h1); ACC8(e2, h2); ACC8(e3, h3); ACC8(e4, h4);
    }
    if (i < deg) {                      // masked tail (1..3 edges)
        const int j2 = (i + 1 < deg) ? (i + 1) : i;
        const int j3 = (i + 2 < deg) ? (i + 2) : i;
        const u32 p1 = csrE[beg + i];
        const u32 p2 = csrE[beg + j2];
        const u32 p3 = csrE[beg + j3];
        const uint4 h1 = ((const uint4*)(hin + (size_t)(p1 & 0xFFFFu) * F))[l];
        const uint4 h2 = ((const uint4*)(hin + (size_t)(p2 & 0xFFFFu) * F))[l];
        const uint4 h3 = ((const uint4*)(hin + (size_t)(p3 & 0xFFFFu) * F))[l];
        const float e1 = __half2float(__ushort_as_half((u16)(p1 >> 16)));
        const float e2 = (i + 1 < deg) ? __half2float(__ushort_as_half((u16)(p2 >> 16))) : 0.f;
        const float e3 = (i + 2 < deg) ? __half2float(__ushort_as_half((u16)(p3 >> 16))) : 0.f;
        z += e1 + e2 + e3;
        ACC8(e1, h1); ACC8(e2, h2); ACC8(e3, h3);
    }
    // ---- self loop (never staged): ev = exp(lrelu(as[n] + ad[n]))
    if (n < nr) {
        float r = asnn[n] + advn[n];
        r = (r > 0.f) ? r : 0.2f * r;
        const float ev = __expf(r);
        const uint4 hs = ((const uint4*)(hin + (size_t)(nbase + n) * F))[l];
        z += ev;
        ACC8(ev, hs);
    }

    const float inv = 1.f / (z + 1e-16f);
    const float4 b0v = *(const float4*)&bias[l * 8];
    const float4 b1v = *(const float4*)&bias[l * 8 + 4];
    float v0 = a0 * inv + b0v.x, v1 = a1 * inv + b0v.y;
    float v2 = a2 * inv + b0v.z, v3 = a3 * inv + b0v.w;
    float v4 = a4 * inv + b1v.x, v5 = a5 * inv + b1v.y;
    float v6 = a6 * inv + b1v.z, v7 = a7 * inv + b1v.w;
    v0 = (v0 > 0.f) ? v0 : 0.01f * v0;  v1 = (v1 > 0.f) ? v1 : 0.01f * v1;
    v2 = (v2 > 0.f) ? v2 : 0.01f * v2;  v3 = (v3 > 0.f) ? v3 : 0.01f * v3;
    v4 = (v4 > 0.f) ? v4 : 0.01f * v4;  v5 = (v5 > 0.f) ? v5 : 0.01f * v5;
    v6 = (v6 > 0.f) ? v6 : 0.01f * v6;  v7 = (v7 > 0.f) ? v7 : 0.01f * v7;

    if constexpr (MODE == 0) {
        {
            float4 w0; w0.x = v0; w0.y = v1; w0.z = v2; w0.w = v3;
            float4 w1; w1.x = v4; w1.y = v5; w1.z = v6; w1.w = v7;
            const int xb = n * XSP + l * 8;
            *(float4*)&xs[xb]     = w0;
            *(float4*)&xs[xb + 4] = w1;
        }
        __syncthreads();

        const int nb2 = tid >> 3;          // node 0..63
        const int c0  = (tid & 7) * 8;     // 8 output cols
        float o0=0.f,o1=0.f,o2=0.f,o3=0.f,o4=0.f,o5=0.f,o6=0.f,o7=0.f;
#pragma unroll 8
        for (int k = 0; k < F; ++k) {
            const float xv = xs[nb2 * XSP + k];
            const float4 wa = *(const float4*)&Ws[k * F + c0];
            const float4 wb = *(const float4*)&Ws[k * F + c0 + 4];
            o0 = fmaf(xv, wa.x, o0); o1 = fmaf(xv, wa.y, o1);
            o2 = fmaf(xv, wa.z, o2); o3 = fmaf(xv, wa.w, o3);
            o4 = fmaf(xv, wb.x, o4); o5 = fmaf(xv, wb.y, o5);
            o6 = fmaf(xv, wb.z, o6); o7 = fmaf(xv, wb.w, o7);
        }
        float vs = o0*asv[c0]   + o1*asv[c0+1] + o2*asv[c0+2] + o3*asv[c0+3]
                 + o4*asv[c0+4] + o5*asv[c0+5] + o6*asv[c0+6] + o7*asv[c0+7];
        float vd = o0*adv[c0]   + o1*adv[c0+1] + o2*adv[c0+2] + o3*adv[c0+3]
                 + o4*adv[c0+4] + o5*adv[c0+5] + o6*adv[c0+6] + o7*adv[c0+7];
        vs += __shfl_xor(vs, 1, 64); vs += __shfl_xor(vs, 2, 64); vs += __shfl_xor(vs, 4, 64);
        vd += __shfl_xor(vd, 1, 64); vd += __shfl_xor(vd, 2, 64); vd += __shfl_xor(vd, 4, 64);
        if (nb2 < nr) {
            const int node2 = nbase + nb2;
            if ((tid & 7) == 0) { as_out[node2] = vs; ad_out[node2] = vd; }
            uint4 p;
            p.x = f2bf2(o0, o1); p.y = f2bf2(o2, o3);
            p.z = f2bf2(o4, o5); p.w = f2bf2(o6, o7);
            *(uint4*)&hout[(size_t)node2 * F + c0] = p;
        }
    } else {
        if (n < nr) {
            const int node = nbase + n;
            const float4 r0 = *(const float4*)(resid + (size_t)node * F + l * 8);
            const float4 r1 = *(const float4*)(resid + (size_t)node * F + l * 8 + 4);
            float4 o0, o1;
            o0.x = v0 + r0.x; o0.y = v1 + r0.y; o0.z = v2 + r0.z; o0.w = v3 + r0.w;
            o1.x = v4 + r1.x; o1.y = v5 + r1.y; o1.z = v6 + r1.z; o1.w = v7 + r1.w;
            *(float4*)(out + (size_t)node * F + l * 8)     = o0;
            *(float4*)(out + (size_t)node * F + l * 8 + 4) = o1;
        }
    }
}

extern "C" void kernel_launch(void* const* d_in, const int* in_sizes, int n_in,
                              void* d_out, int out_size, void* d_ws, size_t ws_size,
                              hipStream_t stream)
{
    const float* x   = (const float*)d_in[0];
    const int*   ei  = (const int*)  d_in[1];   // [2, NEDGES] row-major
    const float* W0  = (const float*)d_in[2];
    const float* as0 = (const float*)d_in[3];
    const float* ad0 = (const float*)d_in[4];
    const float* b0  = (const float*)d_in[5];
    const float* W1  = (const float*)d_in[6];
    const float* as1 = (const float*)d_in[7];
    const float* ad1 = (const float*)d_in[8];
    const float* b1  = (const float*)d_in[9];
    float* out = (float*)d_out;

    const int* src = ei;
    const int* dst = ei + NEDGES;

    // workspace carve-up (~18 MB)
    char* ws = (char*)d_ws;
    u16*   h16    = (u16*)ws;   ws += (size_t)NNODES * F * 2;   // layer-1 h
    u16*   h2_16  = (u16*)ws;   ws += (size_t)NNODES * F * 2;   // layer-2 h
    float* as_    = (float*)ws; ws += (size_t)NNODES * 4;
    float* ad_    = (float*)ws; ws += (size_t)NNODES * 4;
    float* as2    = (float*)ws; ws += (size_t)NNODES * 4;
    float* ad2    = (float*)ws; ws += (size_t)NNODES * 4;
    int*   gcur   = (int*)ws;   ws += (size_t)NB * 4;
    u32*   stg    = (u32*)ws;   ws += (size_t)NB * CAP * 4;

    hipMemsetAsync(gcur, 0, (size_t)NB * 4, stream);
    stage_linear1<<<SBLK + LIN_BLOCKS, 256, 0, stream>>>(
        x, W0, as0, ad0, h16, as_, ad_, src, dst, gcur, stg);

    // layer-1 aggregate (+LDS CSR build) + fused layer-2 linear
    gat_agg<0><<<NB, 512, 0, stream>>>(
        gcur, stg, h16, as_, ad_, b0,
        W1, as1, ad1, h2_16, as2, ad2, nullptr, nullptr);
    // layer-2 aggregate (+LDS CSR build) + residual
    gat_agg<1><<<NB, 512, 0, stream>>>(
        gcur, stg, h2_16, as2, ad2, b1,
        nullptr, nullptr, nullptr, nullptr, nullptr, nullptr, x, out);
}

// Round 12
// 166.879 us; speedup vs baseline: 1.0085x; 1.0085x over previous
//
#include <hip/hip_runtime.h>
#include <hip/hip_fp16.h>
#include <math.h>

#define NNODES 50000
#define NEDGES 800000
#define F      64
#define NB     782               // ceil(NNODES/64) buckets of 64 nodes
#define CAP    1408              // fixed slots per bucket (max real-edge count ~1150)
#define LIN_BLOCKS 1563          // 32 nodes / block
#define SBLK   256               // staging blocks (1 per CU)
#define SIT    13                // edges/thread in staging (256*256*13 >= NEDGES)
#define SEPB   (256 * SIT)       // 3328 edges per staging block
#define XSP    68                // padded LDS row stride (floats)

typedef unsigned short u16;
typedef unsigned int   u32;

// pack two f32 -> two bf16 (RNE)
__device__ __forceinline__ u32 f2bf2(float a, float b) {
    u32 ua = __float_as_uint(a), ub = __float_as_uint(b);
    ua = (ua + 0x7FFFu + ((ua >> 16) & 1u)) >> 16;
    ub = (ub + 0x7FFFu + ((ub >> 16) & 1u)) >> 16;
    return ua | (ub << 16);
}

#define ACC8(ev, hv) \
    a0 = fmaf(ev, __uint_as_float(hv.x << 16),         a0); \
    a1 = fmaf(ev, __uint_as_float(hv.x & 0xFFFF0000u), a1); \
    a2 = fmaf(ev, __uint_as_float(hv.y << 16),         a2); \
    a3 = fmaf(ev, __uint_as_float(hv.y & 0xFFFF0000u), a3); \
    a4 = fmaf(ev, __uint_as_float(hv.z << 16),         a4); \
    a5 = fmaf(ev, __uint_as_float(hv.z & 0xFFFF0000u), a5); \
    a6 = fmaf(ev, __uint_as_float(hv.w << 16),         a6); \
    a7 = fmaf(ev, __uint_as_float(hv.w & 0xFFFF0000u), a7)

// shared-memory layout for the linear body (aliased by the stage path)
struct LinSmem {
    float Ws[F * F];          // 16 KB
    float xs[32 * XSP];       // 8.7 KB
    float asv[F], adv[F];
};

// ---------------------------------------------------------------------------
// Linear body: h16 = bf16(x @ W) ; as_ = (xW).a_src ; ad_ = (xW).a_dst
// 32 nodes / block; 8 lanes per node, 8 output cols per lane.
// ---------------------------------------------------------------------------
__device__ __forceinline__ void linear_body(
    LinSmem& sm,
    const float* __restrict__ x, const float* __restrict__ W,
    const float* __restrict__ a_src, const float* __restrict__ a_dst,
    u16* __restrict__ h16, float* __restrict__ as_, float* __restrict__ ad_,
    int blk)
{
    const int tid = threadIdx.x;
    const int n   = tid >> 3;          // node within block 0..31
    const int c0  = (tid & 7) * 8;     // output col base
    const int node = blk * 32 + n;
    const bool valid = node < NNODES;

    for (int i = tid * 4; i < F * F; i += 1024)
        *(float4*)&sm.Ws[i] = *(const float4*)&W[i];
    if (tid < F) { sm.asv[tid] = a_src[tid]; sm.adv[tid] = a_dst[tid]; }
    if (valid) {
        const float4 v0 = *(const float4*)&x[(size_t)node * F + c0];
        const float4 v1 = *(const float4*)&x[(size_t)node * F + c0 + 4];
        *(float4*)&sm.xs[n * XSP + c0]     = v0;
        *(float4*)&sm.xs[n * XSP + c0 + 4] = v1;
    }
    __syncthreads();

    float o0=0.f,o1=0.f,o2=0.f,o3=0.f,o4=0.f,o5=0.f,o6=0.f,o7=0.f;
#pragma unroll 8
    for (int k = 0; k < F; ++k) {
        const float xv = sm.xs[n * XSP + k];
        const float4 wa = *(const float4*)&sm.Ws[k * F + c0];
        const float4 wb = *(const float4*)&sm.Ws[k * F + c0 + 4];
        o0 = fmaf(xv, wa.x, o0); o1 = fmaf(xv, wa.y, o1);
        o2 = fmaf(xv, wa.z, o2); o3 = fmaf(xv, wa.w, o3);
        o4 = fmaf(xv, wb.x, o4); o5 = fmaf(xv, wb.y, o5);
        o6 = fmaf(xv, wb.z, o6); o7 = fmaf(xv, wb.w, o7);
    }

    float vs = o0*sm.asv[c0]   + o1*sm.asv[c0+1] + o2*sm.asv[c0+2] + o3*sm.asv[c0+3]
             + o4*sm.asv[c0+4] + o5*sm.asv[c0+5] + o6*sm.asv[c0+6] + o7*sm.asv[c0+7];
    float vd = o0*sm.adv[c0]   + o1*sm.adv[c0+1] + o2*sm.adv[c0+2] + o3*sm.adv[c0+3]
             + o4*sm.adv[c0+4] + o5*sm.adv[c0+5] + o6*sm.adv[c0+6] + o7*sm.adv[c0+7];
    vs += __shfl_xor(vs, 1, 64); vs += __shfl_xor(vs, 2, 64); vs += __shfl_xor(vs, 4, 64);
    vd += __shfl_xor(vd, 1, 64); vd += __shfl_xor(vd, 2, 64); vd += __shfl_xor(vd, 4, 64);

    if (valid) {
        if ((tid & 7) == 0) { as_[node] = vs; ad_[node] = vd; }
        uint4 p;
        p.x = f2bf2(o0, o1); p.y = f2bf2(o2, o3);
        p.z = f2bf2(o4, o5); p.w = f2bf2(o6, o7);
        *(uint4*)&h16[(size_t)node * F + c0] = p;
    }
}

// ---------------------------------------------------------------------------
// K1: blocks [0,SBLK): stage REAL edges (no self loops) into fixed-CAP bucket
//     regions. Register-light two-pass form (r10): hist atomics, reserve,
//     re-read + scatter atomics (second read is L2-hot).
//     blocks [SBLK..): layer-1 linear (stage latency hides under it).
// ---------------------------------------------------------------------------
__global__ __launch_bounds__(256) void stage_linear1(
    const float* __restrict__ x, const float* __restrict__ W,
    const float* __restrict__ a_src, const float* __restrict__ a_dst,
    u16* __restrict__ h16, float* __restrict__ as_, float* __restrict__ ad_,
    const int* __restrict__ src, const int* __restrict__ dst,
    int* __restrict__ gcur, u32* __restrict__ stg)
{
    __shared__ LinSmem sm;
    if (blockIdx.x < SBLK) {
        int* cnt  = (int*)&sm;          // NB ints
        int* lcur = cnt + NB;           // NB ints (aliases sm)
        for (int i = threadIdx.x; i < NB; i += 256) cnt[i] = 0;
        __syncthreads();
        const int base = blockIdx.x * SEPB;
#pragma unroll
        for (int it = 0; it < SIT; ++it) {
            const int e = base + it * 256 + threadIdx.x;
            if (e < NEDGES) atomicAdd(&cnt[dst[e] >> 6], 1);
        }
        __syncthreads();
        for (int i = threadIdx.x; i < NB; i += 256)
            lcur[i] = cnt[i] ? (i * CAP + atomicAdd(&gcur[i], cnt[i])) : 0;
        __syncthreads();
#pragma unroll
        for (int it = 0; it < SIT; ++it) {
            const int e = base + it * 256 + threadIdx.x;
            if (e < NEDGES) {
                const int s = src[e], d = dst[e];
                const int p = atomicAdd(&lcur[d >> 6], 1);
                stg[p] = ((u32)(d & 63) << 16) | (u32)s;
            }
        }
        return;
    }
    linear_body(sm, x, W, a_src, a_dst, h16, as_, ad_, blockIdx.x - SBLK);
}

// ---------------------------------------------------------------------------
// K2: layer-1 aggregate. Per-bucket LDS CSR build with ONE LDS-atomic pass
// (hist return value = slot, held in registers; scatter atomic-free).
// During scatter, write back the SORTED edge list to stg and persist
// rp32[node] = beg | deg<<12 -- so K3 needs no hist/scan/atomics at all.
// Self-loop handled inline (never staged). Epilogue: fused layer-2 linear.
// ---------------------------------------------------------------------------
#define BITER 3   // ceil(CAP/512)
__global__ __launch_bounds__(512) void gat_agg0(
    const int* __restrict__ gcur, u32* __restrict__ stg,
    const u16* __restrict__ hin,
    const float* __restrict__ as_, const float* __restrict__ ad_,
    const float* __restrict__ bias,
    const float* __restrict__ Wn, const float* __restrict__ an_s,
    const float* __restrict__ an_d,
    u16* __restrict__ hout, float* __restrict__ as_out, float* __restrict__ ad_out,
    u32* __restrict__ rp32)
{
    __shared__ u32  csrE[CAP];
    __shared__ int  cnt[64];     // hist counts (= deg after pass 1)
    __shared__ int  rp[64];      // local exclusive rowptr
    __shared__ float advn[64];   // ad_ for bucket nodes
    __shared__ float asnn[64];   // as_ for bucket nodes (self-loop term)
    __shared__ float Ws[F * F];
    __shared__ float asv[F], adv[F];
    __shared__ float xs[64 * XSP];

    const int tid   = threadIdx.x;
    const int b     = blockIdx.x;
    const int nbase = b << 6;
    const int nr    = (NNODES - nbase < 64) ? (NNODES - nbase) : 64;
    const int m     = gcur[b];

    if (tid < 64) {
        cnt[tid]  = 0;
        const bool v = tid < nr;
        advn[tid] = v ? ad_[nbase + tid] : 0.f;
        asnn[tid] = v ? as_[nbase + tid] : 0.f;
    }
    for (int i = tid * 4; i < F * F; i += 2048)
        *(float4*)&Ws[i] = *(const float4*)&Wn[i];
    if (tid < F) { asv[tid] = an_s[tid]; adv[tid] = an_d[tid]; }
    __syncthreads();

    // ---- pass 1: hist; the atomic's return value is the per-node slot
    u32 pk_[BITER]; int po_[BITER];
#pragma unroll
    for (int it = 0; it < BITER; ++it) {
        const int i = tid + it * 512;
        if (i < m) {
            const u32 pk = stg[b * CAP + i];
            pk_[it] = pk;
            po_[it] = atomicAdd(&cnt[pk >> 16], 1);
        } else po_[it] = -1;
    }
    __syncthreads();
    // ---- scan (wave 0); persist rp32 for layer 2
    if (tid < 64) {
        const int v = cnt[tid];
        int incl = v;
#pragma unroll
        for (int off = 1; off < 64; off <<= 1) {
            const int t = __shfl_up(incl, off, 64);
            if (tid >= off) incl += t;
        }
        rp[tid] = incl - v;
        if (tid < nr) rp32[nbase + tid] = (u32)(incl - v) | ((u32)v << 12);
    }
    __syncthreads();
    // ---- scatter (atomic-free) + per-edge attention weight + sorted stg
#pragma unroll
    for (int it = 0; it < BITER; ++it) {
        if (po_[it] >= 0) {
            const u32 pk = pk_[it];
            const int d6 = pk >> 16;
            const int s  = pk & 0xFFFFu;
            float r = as_[s] + advn[d6];
            r = (r > 0.f) ? r : 0.2f * r;
            const float ev = __expf(r);
            const int idx = rp[d6] + po_[it];
            csrE[idx] = ((u32)__half_as_ushort(__float2half(ev)) << 16) | (u32)s;
            stg[b * CAP + idx] = pk;     // sorted write-back for layer 2
        }
    }
    __syncthreads();

    // ---- aggregate: 8 lanes per node
    const int n   = tid >> 3;
    const int l   = tid & 7;
    const int beg = rp[n];
    const int deg = cnt[n];

    float a0=0.f,a1=0.f,a2=0.f,a3=0.f,a4=0.f,a5=0.f,a6=0.f,a7=0.f;
    float z = 0.f;
    const int nfull = deg & ~3;
    int i = 0;
    for (; i < nfull; i += 4) {
        const u32 p1 = csrE[beg + i];
        const u32 p2 = csrE[beg + i + 1];
        const u32 p3 = csrE[beg + i + 2];
        const u32 p4 = csrE[beg + i + 3];
        const uint4 h1 = ((const uint4*)(hin + (size_t)(p1 & 0xFFFFu) * F))[l];
        const uint4 h2 = ((const uint4*)(hin + (size_t)(p2 & 0xFFFFu) * F))[l];
        const uint4 h3 = ((const uint4*)(hin + (size_t)(p3 & 0xFFFFu) * F))[l];
        const uint4 h4 = ((const uint4*)(hin + (size_t)(p4 & 0xFFFFu) * F))[l];
        const float e1 = __half2float(__ushort_as_half((u16)(p1 >> 16)));
        const float e2 = __half2float(__ushort_as_half((u16)(p2 >> 16)));
        const float e3 = __half2float(__ushort_as_half((u16)(p3 >> 16)));
        const float e4 = __half2float(__ushort_as_half((u16)(p4 >> 16)));
        z += (e1 + e2) + (e3 + e4);
        ACC8(e1, h1); ACC8(e2, h2); ACC8(e3, h3); ACC8(e4, h4);
    }
    if (i < deg) {
        const int j2 = (i + 1 < deg) ? (i + 1) : i;
        const int j3 = (i + 2 < deg) ? (i + 2) : i;
        const u32 p1 = csrE[beg + i];
        const u32 p2 = csrE[beg + j2];
        const u32 p3 = csrE[beg + j3];
        const uint4 h1 = ((const uint4*)(hin + (size_t)(p1 & 0xFFFFu) * F))[l];
        const uint4 h2 = ((const uint4*)(hin + (size_t)(p2 & 0xFFFFu) * F))[l];
        const uint4 h3 = ((const uint4*)(hin + (size_t)(p3 & 0xFFFFu) * F))[l];
        const float e1 = __half2float(__ushort_as_half((u16)(p1 >> 16)));
        const float e2 = (i + 1 < deg) ? __half2float(__ushort_as_half((u16)(p2 >> 16))) : 0.f;
        const float e3 = (i + 2 < deg) ? __half2float(__ushort_as_half((u16)(p3 >> 16))) : 0.f;
        z += e1 + e2 + e3;
        ACC8(e1, h1); ACC8(e2, h2); ACC8(e3, h3);
    }
    // self loop (never staged)
    if (n < nr) {
        float r = asnn[n] + advn[n];
        r = (r > 0.f) ? r : 0.2f * r;
        const float ev = __expf(r);
        const uint4 hs = ((const uint4*)(hin + (size_t)(nbase + n) * F))[l];
        z += ev;
        ACC8(ev, hs);
    }

    const float inv = 1.f / (z + 1e-16f);
    const float4 b0v = *(const float4*)&bias[l * 8];
    const float4 b1v = *(const float4*)&bias[l * 8 + 4];
    float v0 = a0 * inv + b0v.x, v1 = a1 * inv + b0v.y;
    float v2 = a2 * inv + b0v.z, v3 = a3 * inv + b0v.w;
    float v4 = a4 * inv + b1v.x, v5 = a5 * inv + b1v.y;
    float v6 = a6 * inv + b1v.z, v7 = a7 * inv + b1v.w;
    v0 = (v0 > 0.f) ? v0 : 0.01f * v0;  v1 = (v1 > 0.f) ? v1 : 0.01f * v1;
    v2 = (v2 > 0.f) ? v2 : 0.01f * v2;  v3 = (v3 > 0.f) ? v3 : 0.01f * v3;
    v4 = (v4 > 0.f) ? v4 : 0.01f * v4;  v5 = (v5 > 0.f) ? v5 : 0.01f * v5;
    v6 = (v6 > 0.f) ? v6 : 0.01f * v6;  v7 = (v7 > 0.f) ? v7 : 0.01f * v7;

    // stash activated rows; fused layer-2 linear
    {
        float4 w0; w0.x = v0; w0.y = v1; w0.z = v2; w0.w = v3;
        float4 w1; w1.x = v4; w1.y = v5; w1.z = v6; w1.w = v7;
        const int xb = n * XSP + l * 8;
        *(float4*)&xs[xb]     = w0;
        *(float4*)&xs[xb + 4] = w1;
    }
    __syncthreads();

    const int nb2 = tid >> 3;
    const int c0  = (tid & 7) * 8;
    float o0=0.f,o1=0.f,o2=0.f,o3=0.f,o4=0.f,o5=0.f,o6=0.f,o7=0.f;
#pragma unroll 8
    for (int k = 0; k < F; ++k) {
        const float xv = xs[nb2 * XSP + k];
        const float4 wa = *(const float4*)&Ws[k * F + c0];
        const float4 wb = *(const float4*)&Ws[k * F + c0 + 4];
        o0 = fmaf(xv, wa.x, o0); o1 = fmaf(xv, wa.y, o1);
        o2 = fmaf(xv, wa.z, o2); o3 = fmaf(xv, wa.w, o3);
        o4 = fmaf(xv, wb.x, o4); o5 = fmaf(xv, wb.y, o5);
        o6 = fmaf(xv, wb.z, o6); o7 = fmaf(xv, wb.w, o7);
    }
    float vs = o0*asv[c0]   + o1*asv[c0+1] + o2*asv[c0+2] + o3*asv[c0+3]
             + o4*asv[c0+4] + o5*asv[c0+5] + o6*asv[c0+6] + o7*asv[c0+7];
    float vd = o0*adv[c0]   + o1*adv[c0+1] + o2*adv[c0+2] + o3*adv[c0+3]
             + o4*adv[c0+4] + o5*adv[c0+5] + o6*adv[c0+6] + o7*adv[c0+7];
    vs += __shfl_xor(vs, 1, 64); vs += __shfl_xor(vs, 2, 64); vs += __shfl_xor(vs, 4, 64);
    vd += __shfl_xor(vd, 1, 64); vd += __shfl_xor(vd, 2, 64); vd += __shfl_xor(vd, 4, 64);
    if (nb2 < nr) {
        const int node2 = nbase + nb2;
        if ((tid & 7) == 0) { as_out[node2] = vs; ad_out[node2] = vd; }
        uint4 p;
        p.x = f2bf2(o0, o1); p.y = f2bf2(o2, o3);
        p.z = f2bf2(o4, o5); p.w = f2bf2(o6, o7);
        *(uint4*)&hout[(size_t)node2 * F + c0] = p;
    }
}

// ---------------------------------------------------------------------------
// K3: layer-2 aggregate. stg is SORTED and rp32 persisted -> build phase is a
// plain parallel pass: no hist, no scan, no LDS atomics. Epilogue: +residual.
// ---------------------------------------------------------------------------
__global__ __launch_bounds__(512) void gat_agg1(
    const int* __restrict__ gcur, const u32* __restrict__ stg,
    const u16* __restrict__ hin,
    const float* __restrict__ as_, const float* __restrict__ ad_,
    const float* __restrict__ bias, const u32* __restrict__ rp32,
    const float* __restrict__ resid, float* __restrict__ out)
{
    __shared__ u32  csrE[CAP];
    __shared__ int  rp[64];
    __shared__ int  dg[64];
    __shared__ float advn[64];
    __shared__ float asnn[64];

    const int tid   = threadIdx.x;
    const int b     = blockIdx.x;
    const int nbase = b << 6;
    const int nr    = (NNODES - nbase < 64) ? (NNODES - nbase) : 64;
    const int m     = gcur[b];

    if (tid < 64) {
        const bool v = tid < nr;
        const u32 r = v ? rp32[nbase + tid] : 0;
        rp[tid] = r & 0xFFFu;
        dg[tid] = r >> 12;
        advn[tid] = v ? ad_[nbase + tid] : 0.f;
        asnn[tid] = v ? as_[nbase + tid] : 0.f;
    }
    __syncthreads();

    // ---- build: plain pass over sorted stg (no atomics)
    for (int i = tid; i < m; i += 512) {
        const u32 pk = stg[b * CAP + i];
        const int d6 = pk >> 16;
        const int s  = pk & 0xFFFFu;
        float r = as_[s] + advn[d6];
        r = (r > 0.f) ? r : 0.2f * r;
        const float ev = __expf(r);
        csrE[i] = ((u32)__half_as_ushort(__float2half(ev)) << 16) | (u32)s;
    }
    __syncthreads();

    // ---- aggregate: 8 lanes per node
    const int n   = tid >> 3;
    const int l   = tid & 7;
    const int beg = rp[n];
    const int deg = dg[n];

    float a0=0.f,a1=0.f,a2=0.f,a3=0.f,a4=0.f,a5=0.f,a6=0.f,a7=0.f;
    float z = 0.f;
    const int nfull = deg & ~3;
    int i = 0;
    for (; i < nfull; i += 4) {
        const u32 p1 = csrE[beg + i];
        const u32 p2 = csrE[beg + i + 1];
        const u32 p3 = csrE[beg + i + 2];
        const u32 p4 = csrE[beg + i + 3];
        const uint4 h1 = ((const uint4*)(hin + (size_t)(p1 & 0xFFFFu) * F))[l];
        const uint4 h2 = ((const uint4*)(hin + (size_t)(p2 & 0xFFFFu) * F))[l];
        const uint4 h3 = ((const uint4*)(hin + (size_t)(p3 & 0xFFFFu) * F))[l];
        const uint4 h4 = ((const uint4*)(hin + (size_t)(p4 & 0xFFFFu) * F))[l];
        const float e1 = __half2float(__ushort_as_half((u16)(p1 >> 16)));
        const float e2 = __half2float(__ushort_as_half((u16)(p2 >> 16)));
        const float e3 = __half2float(__ushort_as_half((u16)(p3 >> 16)));
        const float e4 = __half2float(__ushort_as_half((u16)(p4 >> 16)));
        z += (e1 + e2) + (e3 + e4);
        ACC8(e1, h1); ACC8(e2, h2); ACC8(e3, h3); ACC8(e4, h4);
    }
    if (i < deg) {
        const int j2 = (i + 1 < deg) ? (i + 1) : i;
        const int j3 = (i + 2 < deg) ? (i + 2) : i;
        const u32 p1 = csrE[beg + i];
        const u32 p2 = csrE[beg + j2];
        const u32 p3 = csrE[beg + j3];
        const uint4 h1 = ((const uint4*)(hin + (size_t)(p1 & 0xFFFFu) * F))[l];
        const uint4 h2 = ((const uint4*)(hin + (size_t)(p2 & 0xFFFFu) * F))[l];
        const uint4 h3 = ((const uint4*)(hin + (size_t)(p3 & 0xFFFFu) * F))[l];
        const float e1 = __half2float(__ushort_as_half((u16)(p1 >> 16)));
        const float e2 = (i + 1 < deg) ? __half2float(__ushort_as_half((u16)(p2 >> 16))) : 0.f;
        const float e3 = (i + 2 < deg) ? __half2float(__ushort_as_half((u16)(p3 >> 16))) : 0.f;
        z += e1 + e2 + e3;
        ACC8(e1, h1); ACC8(e2, h2); ACC8(e3, h3);
    }
    // self loop
    if (n < nr) {
        float r = asnn[n] + advn[n];
        r = (r > 0.f) ? r : 0.2f * r;
        const float ev = __expf(r);
        const uint4 hs = ((const uint4*)(hin + (size_t)(nbase + n) * F))[l];
        z += ev;
        ACC8(ev, hs);
    }

    if (n < nr) {
        const int node = nbase + n;
        const float inv = 1.f / (z + 1e-16f);
        const float4 b0v = *(const float4*)&bias[l * 8];
        const float4 b1v = *(const float4*)&bias[l * 8 + 4];
        float v0 = a0 * inv + b0v.x, v1 = a1 * inv + b0v.y;
        float v2 = a2 * inv + b0v.z, v3 = a3 * inv + b0v.w;
        float v4 = a4 * inv + b1v.x, v5 = a5 * inv + b1v.y;
        float v6 = a6 * inv + b1v.z, v7 = a7 * inv + b1v.w;
        v0 = (v0 > 0.f) ? v0 : 0.01f * v0;  v1 = (v1 > 0.f) ? v1 : 0.01f * v1;
        v2 = (v2 > 0.f) ? v2 : 0.01f * v2;  v3 = (v3 > 0.f) ? v3 : 0.01f * v3;
        v4 = (v4 > 0.f) ? v4 : 0.01f * v4;  v5 = (v5 > 0.f) ? v5 : 0.01f * v5;
        v6 = (v6 > 0.f) ? v6 : 0.01f * v6;  v7 = (v7 > 0.f) ? v7 : 0.01f * v7;
        const float4 r0 = *(const float4*)(resid + (size_t)node * F + l * 8);
        const float4 r1 = *(const float4*)(resid + (size_t)node * F + l * 8 + 4);
        float4 o0, o1;
        o0.x = v0 + r0.x; o0.y = v1 + r0.y; o0.z = v2 + r0.z; o0.w = v3 + r0.w;
        o1.x = v4 + r1.x; o1.y = v5 + r1.y; o1.z = v6 + r1.z; o1.w = v7 + r1.w;
        *(float4*)(out + (size_t)node * F + l * 8)     = o0;
        *(float4*)(out + (size_t)node * F + l * 8 + 4) = o1;
    }
}

extern "C" void kernel_launch(void* const* d_in, const int* in_sizes, int n_in,
                              void* d_out, int out_size, void* d_ws, size_t ws_size,
                              hipStream_t stream)
{
    const float* x   = (const float*)d_in[0];
    const int*   ei  = (const int*)  d_in[1];   // [2, NEDGES] row-major
    const float* W0  = (const float*)d_in[2];
    const float* as0 = (const float*)d_in[3];
    const float* ad0 = (const float*)d_in[4];
    const float* b0  = (const float*)d_in[5];
    const float* W1  = (const float*)d_in[6];
    const float* as1 = (const float*)d_in[7];
    const float* ad1 = (const float*)d_in[8];
    const float* b1  = (const float*)d_in[9];
    float* out = (float*)d_out;

    const int* src = ei;
    const int* dst = ei + NEDGES;

    // workspace carve-up (~18 MB)
    char* ws = (char*)d_ws;
    u16*   h16    = (u16*)ws;   ws += (size_t)NNODES * F * 2;   // layer-1 h
    u16*   h2_16  = (u16*)ws;   ws += (size_t)NNODES * F * 2;   // layer-2 h
    float* as_    = (float*)ws; ws += (size_t)NNODES * 4;
    float* ad_    = (float*)ws; ws += (size_t)NNODES * 4;
    float* as2    = (float*)ws; ws += (size_t)NNODES * 4;
    float* ad2    = (float*)ws; ws += (size_t)NNODES * 4;
    u32*   rp32   = (u32*)ws;   ws += (size_t)NNODES * 4;
    int*   gcur   = (int*)ws;   ws += (size_t)NB * 4;
    u32*   stg    = (u32*)ws;   ws += (size_t)NB * CAP * 4;

    hipMemsetAsync(gcur, 0, (size_t)NB * 4, stream);
    stage_linear1<<<SBLK + LIN_BLOCKS, 256, 0, stream>>>(
        x, W0, as0, ad0, h16, as_, ad_, src, dst, gcur, stg);

    // layer-1 aggregate (1-atomic-pass CSR build, persists sorted stg + rp32)
    // + fused layer-2 linear
    gat_agg0<<<NB, 512, 0, stream>>>(
        gcur, stg, h16, as_, ad_, b0,
        W1, as1, ad1, h2_16, as2, ad2, rp32);
    // layer-2 aggregate (atomic-free build) + residual
    gat_agg1<<<NB, 512, 0, stream>>>(
        gcur, stg, h2_16, as2, ad2, b1, rp32, x, out);
}